// Round 3
// baseline (573.037 us; speedup 1.0000x reference)
//
#include <hip/hip_runtime.h>
#include <hip/hip_bf16.h>
#include <stdint.h>

#define N_TOK 4096
#define DIM   1024
#define NE    8
#define HID   4096
#define OUTD  1024
#define TOPK  2
#define SLOTS (N_TOK*TOPK)
#define SLOTS_PAD (SLOTS+128)

typedef __bf16 bf16_t;
typedef __attribute__((ext_vector_type(8))) __bf16 bf16x8;
typedef __attribute__((ext_vector_type(4))) __bf16 bf16x4;
typedef __attribute__((ext_vector_type(4))) float  f32x4;

// ---------------- fused gating (fp64 logits, top-2, softmax) + x -> bf16 cast ----------------
__global__ void k_gatecast(const float* __restrict__ x, const float* __restrict__ wg,
                           bf16_t* __restrict__ xb,
                           int* __restrict__ tki, float* __restrict__ tkg,
                           int* __restrict__ counts) {
    int n = blockIdx.x;
    int lane = threadIdx.x;            // 64 threads = 1 wave
    const float* xr = x + (size_t)n * DIM;
    double acc[NE];
#pragma unroll
    for (int e = 0; e < NE; ++e) acc[e] = 0.0;
#pragma unroll
    for (int i = 0; i < 4; ++i) {
        int d0 = i * 256 + lane * 4;
        float4 v = *(const float4*)&xr[d0];
        bf16x4 o;
        o[0] = (__bf16)v.x; o[1] = (__bf16)v.y; o[2] = (__bf16)v.z; o[3] = (__bf16)v.w;
        *(bf16x4*)&xb[(size_t)n * DIM + d0] = o;
        const float* wr = wg + (size_t)d0 * NE;
#pragma unroll
        for (int j = 0; j < 4; ++j) {
            double xv = (double)((&v.x)[j]);
#pragma unroll
            for (int e = 0; e < NE; ++e) acc[e] += xv * (double)wr[j * NE + e];
        }
    }
#pragma unroll
    for (int e = 0; e < NE; ++e)
        for (int off = 32; off > 0; off >>= 1) acc[e] += __shfl_xor(acc[e], off);
    if (lane == 0) {
        int i0 = 0; double v0 = acc[0];
#pragma unroll
        for (int e = 1; e < NE; ++e) if (acc[e] > v0) { v0 = acc[e]; i0 = e; }
        int i1 = -1; double v1 = -1e300;
#pragma unroll
        for (int e = 0; e < NE; ++e) if (e != i0 && acc[e] > v1) { v1 = acc[e]; i1 = e; }
        double e1 = exp(v1 - v0);
        double s = 1.0 + e1;
        tki[n*2]   = i0;  tki[n*2+1] = i1;
        tkg[n*2]   = (float)(1.0 / s);
        tkg[n*2+1] = (float)(e1 / s);
        atomicAdd(&counts[i0], 1);
        atomicAdd(&counts[i1], 1);
    }
}

// ---------------- importance: deterministic per-expert reduction ----------------
__global__ void k_importance(const int* __restrict__ tki, const float* __restrict__ tkg,
                             float* __restrict__ imp) {
    int e = blockIdx.x, t = threadIdx.x;
    __shared__ float red[256];
    float s = 0.f;
    for (int i = t; i < SLOTS; i += 256) s += (tki[i] == e) ? tkg[i] : 0.f;
    red[t] = s; __syncthreads();
    for (int off = 128; off > 0; off >>= 1) {
        if (t < off) red[t] += red[t + off];
        __syncthreads();
    }
    if (t == 0) imp[e] = red[0];
}

// ---------------- aux loss + prefix-sum bases ----------------
__global__ void k_finalize(const float* __restrict__ imp, const int* __restrict__ counts,
                           int* __restrict__ bases, float* __restrict__ aux_out) {
    if (threadIdx.x == 0 && blockIdx.x == 0) {
        float m = 0.f;
        for (int e = 0; e < NE; ++e) m += imp[e];
        m /= (float)NE;
        float var = 0.f;
        for (int e = 0; e < NE; ++e) { float d = imp[e] - m; var += d * d; }
        var /= (float)NE;
        aux_out[0] = 0.01f * var / (m * m + 1e-10f);
        int b = 0;
        for (int e = 0; e < NE; ++e) { bases[e] = b; b += counts[e]; }
    }
}

// ---------------- build per-expert token lists ----------------
__global__ void k_build(const int* __restrict__ tki, const float* __restrict__ tkg,
                        const int* __restrict__ bases, int* __restrict__ cursor,
                        int* __restrict__ tok_ids, float* __restrict__ sgate) {
    int i = blockIdx.x * 256 + threadIdx.x;
    if (i < SLOTS) {
        int e = tki[i];
        int p = atomicAdd(&cursor[e], 1);
        int s = bases[e] + p;
        tok_ids[s] = i >> 1;
        sgate[s]   = tkg[i];
    }
}

// ---------------- W [E][R][C] fp32 -> Wt [E][C][R] bf16, 64x64 tiles ----------------
// float4 loads, bf16x4 (8B) coalesced stores, padded LDS (2-way max = free).
__global__ void k_transpose(const float* __restrict__ src, bf16_t* __restrict__ dst,
                            int R, int C) {
    __shared__ float tile[64][65];
    const size_t slab = (size_t)R * C;
    const float* s = src + slab * blockIdx.z;
    bf16_t*      d = dst + slab * blockIdx.z;
    int c0 = blockIdx.x * 64, r0 = blockIdx.y * 64;
    int tx = threadIdx.x & 15;
    int ty = threadIdx.x >> 4;
#pragma unroll
    for (int p = 0; p < 4; ++p) {
        int rr = p * 16 + ty;
        float4 v = *(const float4*)&s[(size_t)(r0 + rr) * C + c0 + tx * 4];
        tile[rr][tx*4+0] = v.x; tile[rr][tx*4+1] = v.y;
        tile[rr][tx*4+2] = v.z; tile[rr][tx*4+3] = v.w;
    }
    __syncthreads();
#pragma unroll
    for (int p = 0; p < 4; ++p) {
        int rr = p * 16 + ty;          // dst row (= source column)
        int cc = tx * 4;               // dst col (= source row)
        bf16x4 o;
        o[0] = (__bf16)tile[cc+0][rr]; o[1] = (__bf16)tile[cc+1][rr];
        o[2] = (__bf16)tile[cc+2][rr]; o[3] = (__bf16)tile[cc+3][rr];
        *(bf16x4*)&d[(size_t)(c0 + rr) * R + r0 + cc] = o;
    }
}

// ---------------- grouped GEMM, 128x128 tile, BK=32, 4 waves ----------------
// Depth-3 counted-vmcnt pipeline (T3+T4): 4 LDS buffers; per iter:
//   s_waitcnt vmcnt(8) ; s_barrier ; issue tile kt+3 ; ds_read kt ;
//   lgkmcnt(0)+sched_barrier ; setprio(1) 16xMFMA setprio(0).
// vmcnt never drains to 0 in steady state. XCD-pinned experts; within an XCD,
// 8-panel groups with y inner so A-slices + B-panels (~4MB) stay L2-hot.
// MODE 0: h = relu(x_gather @ W1t^T + b1) -> hbuf (bf16)
// MODE 1: out[token] += gate * (h @ W2t^T + b2)  (atomic, exactly 2 adds/elem)
template <int MODE>
__global__ __launch_bounds__(256, 2)
void k_gemm(const bf16_t* __restrict__ A,    // MODE0: xb [N][DIM]; MODE1: hbuf [SLOTS_PAD][HID]
            const bf16_t* __restrict__ Bt,   // MODE0: w1t [E][HID][DIM]; MODE1: w2t [E][OUTD][HID]
            const float* __restrict__ bias,  // MODE0: b1 [E][HID]; MODE1: b2 [E][OUTD]
            const int* __restrict__ tok_ids,
            const float* __restrict__ sgate,
            const int* __restrict__ bases,
            const int* __restrict__ counts,
            bf16_t* __restrict__ hbuf,
            float* __restrict__ out) {
    constexpr int KD = (MODE == 0) ? DIM : HID;   // K length
    constexpr int ND = (MODE == 0) ? HID : OUTD;  // B-row count
    constexpr int NX = ND / 128;                  // n-panels per expert (32 or 8)
    constexpr int BUF = 128 * 32;                 // elems per LDS buffer (A or B)
    constexpr int KT = KD / 32;

    // --- decode: XCD g = expert; within XCD: panel-group outer, y, panel inner ---
    const int g  = blockIdx.x & 7;
    const int s  = blockIdx.x >> 3;               // [0, NX*32)
    const int pg = s >> 8;                        // panel-group of 8 (MODE1: always 0)
    const int r  = s & 255;
    const int y  = r >> 3;
    const int pl = r & 7;
    const int e  = g;
    const int xq = pg * 8 + pl;

    const int ne = counts[e];
    const int m0 = y * 128;
    if (m0 >= ne) return;
    const int n0 = xq * 128;
    const int b0 = bases[e];

    __shared__ bf16_t lA[4 * BUF];  // 32 KB
    __shared__ bf16_t lB[4 * BUF];  // 32 KB

    const int t    = threadIdx.x;
    const int wave = t >> 6, lane = t & 63;
    const int wm = wave >> 1, wn = wave & 1;
    const int lr = lane & 15, lq = lane >> 4;

    // --- staging setup: waves 0-1 stage A rows, waves 2-3 stage Bt rows ---
    const int tilesel = wave >> 1;
    const int half    = wave & 1;
    const bf16_t* gsrc[4];
    bf16_t*       ldst[4];
#pragma unroll
    for (int pp = 0; pp < 4; ++pp) {
        int row  = half * 64 + pp * 16 + (lane >> 2);
        int slot = lane & 3;
        int gk   = slot ^ ((row >> 1) & 3);   // logical k-group at this physical slot
        if (tilesel == 0) {
            size_t arow;
            if (MODE == 0) {
                int mm  = m0 + row;
                int tok = tok_ids[b0 + (mm < ne ? mm : 0)];
                arow = (size_t)tok * KD;
            } else {
                arow = (size_t)(b0 + m0 + row) * KD;
            }
            gsrc[pp] = A + arow + gk * 8;
            ldst[pp] = lA + (half * 64 + pp * 16) * 32;   // wave-uniform base
        } else {
            gsrc[pp] = Bt + ((size_t)e * ND + n0 + row) * KD + gk * 8;
            ldst[pp] = lB + (half * 64 + pp * 16) * 32;
        }
    }

    // --- LDS fragment read pointers (buffer 0) ---
    const bf16_t* pA[4];
    const bf16_t* pB[4];
#pragma unroll
    for (int i = 0; i < 4; ++i) {
        int rr = wm * 64 + i * 16 + lr;
        pA[i] = lA + rr * 32 + ((lq ^ ((rr >> 1) & 3)) << 3);
    }
#pragma unroll
    for (int j = 0; j < 4; ++j) {
        int rr = wn * 64 + j * 16 + lr;
        pB[j] = lB + rr * 32 + ((lq ^ ((rr >> 1) & 3)) << 3);
    }

    f32x4 acc[4][4];
#pragma unroll
    for (int i = 0; i < 4; ++i)
#pragma unroll
        for (int j = 0; j < 4; ++j) acc[i][j] = (f32x4){0.f, 0.f, 0.f, 0.f};

    // --- prologue: issue tiles 0,1,2 (depth 3; 12 outstanding per wave) ---
#pragma unroll
    for (int pt = 0; pt < 3; ++pt) {
#pragma unroll
        for (int pp = 0; pp < 4; ++pp)
            __builtin_amdgcn_global_load_lds(
                (const __attribute__((address_space(1))) uint32_t*)(gsrc[pp] + (size_t)pt * 32),
                (__attribute__((address_space(3))) uint32_t*)(ldst[pp] + pt * BUF), 16, 0, 0);
    }

    for (int kt = 0; kt < KT; ++kt) {
        // wait: my tile-kt loads landed (never drain to 0 in steady state)
        if (kt < KT - 2)       asm volatile("s_waitcnt vmcnt(8)" ::: "memory");
        else if (kt == KT - 2) asm volatile("s_waitcnt vmcnt(4)" ::: "memory");
        else                   asm volatile("s_waitcnt vmcnt(0)" ::: "memory");
        __builtin_amdgcn_s_barrier();   // all waves' tile-kt loads landed

        // issue tile kt+3 into buf (kt+3)&3 (overwrites buf read at iter kt-1)
        if (kt + 3 < KT) {
            const int nb = (kt + 3) & 3;
#pragma unroll
            for (int pp = 0; pp < 4; ++pp)
                __builtin_amdgcn_global_load_lds(
                    (const __attribute__((address_space(1))) uint32_t*)(gsrc[pp] + (size_t)(kt + 3) * 32),
                    (__attribute__((address_space(3))) uint32_t*)(ldst[pp] + nb * BUF), 16, 0, 0);
        }

        // compute tile kt
        const int cb = kt & 3;
        bf16x8 fa[4], fb[4];
#pragma unroll
        for (int i = 0; i < 4; ++i) fa[i] = *(const bf16x8*)(pA[i] + cb * BUF);
#pragma unroll
        for (int j = 0; j < 4; ++j) fb[j] = *(const bf16x8*)(pB[j] + cb * BUF);
        asm volatile("s_waitcnt lgkmcnt(0)" ::: "memory");
        __builtin_amdgcn_sched_barrier(0);
        __builtin_amdgcn_s_setprio(1);
#pragma unroll
        for (int i = 0; i < 4; ++i)
#pragma unroll
            for (int j = 0; j < 4; ++j)
                acc[i][j] = __builtin_amdgcn_mfma_f32_16x16x32_bf16(fb[j], fa[i], acc[i][j], 0, 0, 0);
        __builtin_amdgcn_s_setprio(0);
    }

    // --- epilogue ---
#pragma unroll
    for (int i = 0; i < 4; ++i) {
        int ml = wm * 64 + i * 16 + lr;
        int gm = m0 + ml;
        bool valid = gm < ne;
        int tok = 0; float gv = 0.f;
        if (MODE == 1 && valid) { tok = tok_ids[b0 + gm]; gv = sgate[b0 + gm]; }
#pragma unroll
        for (int j = 0; j < 4; ++j) {
            int gn = n0 + wn * 64 + j * 16 + lq * 4;
            if (valid) {
                f32x4 bv = *(const f32x4*)&bias[(size_t)e * ND + gn];
                if (MODE == 0) {
                    bf16x4 hv;
#pragma unroll
                    for (int r2 = 0; r2 < 4; ++r2)
                        hv[r2] = (__bf16)fmaxf(acc[i][j][r2] + bv[r2], 0.f);
                    *(bf16x4*)&hbuf[(size_t)(b0 + gm) * HID + gn] = hv;
                } else {
#pragma unroll
                    for (int r2 = 0; r2 < 4; ++r2)
                        atomicAdd(&out[(size_t)tok * OUTD + gn + r2],
                                  gv * (acc[i][j][r2] + bv[r2]));
                }
            }
        }
    }
}

extern "C" void kernel_launch(void* const* d_in, const int* in_sizes, int n_in,
                              void* d_out, int out_size, void* d_ws, size_t ws_size,
                              hipStream_t stream) {
    const float* x  = (const float*)d_in[0];
    const float* wg = (const float*)d_in[1];
    const float* w1 = (const float*)d_in[2];
    const float* b1 = (const float*)d_in[3];
    const float* w2 = (const float*)d_in[4];
    const float* b2 = (const float*)d_in[5];
    float* out = (float*)d_out;

    char* ws = (char*)d_ws;
    size_t o = 0;
    auto alloc = [&](size_t b) { size_t r = o; o = (o + b + 255) & ~(size_t)255; return r; };
    int*    counts  = (int*)(ws + alloc(NE * 4));
    int*    cursor  = (int*)(ws + alloc(NE * 4));
    int*    bases   = (int*)(ws + alloc(NE * 4));
    float*  imp     = (float*)(ws + alloc(NE * 4));
    int*    tki     = (int*)(ws + alloc(SLOTS * 4));
    float*  tkg     = (float*)(ws + alloc(SLOTS * 4));
    int*    tok_ids = (int*)(ws + alloc(SLOTS * 4));
    float*  sgate   = (float*)(ws + alloc(SLOTS * 4));
    bf16_t* xb      = (bf16_t*)(ws + alloc((size_t)N_TOK * DIM * 2));
    bf16_t* w1t     = (bf16_t*)(ws + alloc((size_t)NE * HID * DIM * 2));
    bf16_t* w2t     = (bf16_t*)(ws + alloc((size_t)NE * OUTD * HID * 2));
    bf16_t* hbuf    = (bf16_t*)(ws + alloc((size_t)SLOTS_PAD * HID * 2));
    (void)ws_size; (void)n_in; (void)in_sizes;

    hipMemsetAsync(d_out, 0, (size_t)out_size * 4, stream);   // out must be zero (atomic accum)
    hipMemsetAsync(ws, 0, 1024, stream);                       // counts + cursor

    k_gatecast<<<N_TOK, 64, 0, stream>>>(x, wg, xb, tki, tkg, counts);
    k_transpose<<<dim3(HID / 64, DIM / 64, NE), 256, 0, stream>>>(w1, w1t, DIM, HID);
    k_transpose<<<dim3(OUTD / 64, HID / 64, NE), 256, 0, stream>>>(w2, w2t, HID, OUTD);
    k_importance<<<NE, 256, 0, stream>>>(tki, tkg, imp);
    k_finalize<<<1, 64, 0, stream>>>(imp, counts, bases, out + (size_t)N_TOK * OUTD);
    k_build<<<SLOTS / 256, 256, 0, stream>>>(tki, tkg, bases, cursor, tok_ids, sgate);

    // 1D grids: NE*NX*32 blocks; decode in-kernel
    k_gemm<0><<<NE * (HID / 128) * 32, 256, 0, stream>>>(
        xb, w1t, b1, tok_ids, sgate, bases, counts, hbuf, nullptr);
    k_gemm<1><<<NE * (OUTD / 128) * 32, 256, 0, stream>>>(
        hbuf, w2t, b2, tok_ids, sgate, bases, counts, nullptr, out);
}